// Round 1
// baseline (4917.349 us; speedup 1.0000x reference)
//
#include <hip/hip_runtime.h>

// SimpleMemoryNetwork: T=64,B=128,H=256,NI=2,NO=10, lambda=.95, eta=.5, sample=32, decision=8
// Low-rank fast-weight reformulation: A(tau) = sum_{s<=min(tau,32)} lam^(tau-s)*eta*o_s (x) r_s
// readout_t[b,:] = sum_s lam^(t-1-s)*eta*<r_t[b],o_s[b]> * r_s[b,:]
//
// Persistent cooperative kernel: 256 blocks (16 batch-groups x 16 col-groups), 256 thr.
// 145KB LDS/block -> exactly 1 block/CU -> all 256 blocks co-resident (manual grid barriers).

#define NSTEPS 64
#define BB 128
#define HH 256
#define NSLOT 33

// workspace layout (float offsets)
#define OFF_A   0u         // a_glob[2][128][256]
#define OFF_R   65536u     // r_glob[2][128][256]
#define OFF_RH  131072u    // r_hist[33][128][256]
#define OFF_OH  1212416u   // o_hist[33][128][256]
#define OFF_C   2293760u   // c_buf[64][33][128]
#define OFF_MU  2564096u   // mu_buf[64][256]
#define OFF_CTR 2580480u   // barrier counters (128 ints)
#define WS_FLOATS 2580608u

__global__ __launch_bounds__(256) void smn_init(float* __restrict__ ws,
                                                float* __restrict__ out) {
  unsigned i = blockIdx.x * 256u + threadIdx.x;
  unsigned stride = gridDim.x * 256u;
  for (unsigned k = i; k < 131072u; k += stride) ws[k] = 0.f;            // state slots
  for (unsigned k = i; k < 286848u; k += stride) ws[OFF_C + k] = 0.f;    // c_buf+mu+ctr
  for (unsigned k = i; k < 10240u; k += stride) out[k] = 0.f;            // output
}

__device__ __forceinline__ void grid_barrier(int* __restrict__ ctr, int idx) {
  __threadfence();                 // agent-scope release of this thread's writes
  __syncthreads();                 // all block writes drained (vmcnt(0) before s_barrier)
  if (threadIdx.x == 0) {
    __hip_atomic_fetch_add(&ctr[idx], 1, __ATOMIC_ACQ_REL, __HIP_MEMORY_SCOPE_AGENT);
    while (__hip_atomic_load(&ctr[idx], __ATOMIC_RELAXED, __HIP_MEMORY_SCOPE_AGENT) < 256) {
      __builtin_amdgcn_s_sleep(1);
    }
  }
  __syncthreads();
  // per-wave acquire so every wave's caches are invalidated before reading remote data
  (void)__hip_atomic_load(&ctr[idx], __ATOMIC_ACQUIRE, __HIP_MEMORY_SCOPE_AGENT);
}

__global__ __launch_bounds__(256) void smn_main(
    const float* __restrict__ x_in, const float* __restrict__ W_sr,
    const float* __restrict__ W_ma, const float* __restrict__ W_ro,
    const float* __restrict__ W_ao, const float* __restrict__ W_ar,
    const float* __restrict__ W_ra, const float* __restrict__ W_a,
    const float* __restrict__ W_y,  const float* __restrict__ gvec,
    const float* __restrict__ bvec, float* __restrict__ out,
    float* __restrict__ ws)
{
  // persistent weight column-slices (pad 17 breaks bank conflicts)
  __shared__ float Wa_l[256][17], Wra_l[256][17], War_l[256][17];
  __shared__ float Wro_l[256][17], Wao_l[256][17];
  __shared__ float aST[256][10], rST[256][10];   // state(t) transposed, rows=k, cols=8 batches
  __shared__ float P[256][33];                   // k-split partials
  __shared__ float apply_l[128];
  __shared__ float ops[8][17], o_tile[8][17], r_tile[8][17];
  __shared__ float x_l[8][5];
  __shared__ float Wma_l[3][16], Wsr_l[2][16], Wy_l[16][10];
  __shared__ float g_l[16], b_l[16], lam_pow[64];

  const int tid = threadIdx.x;
  const int bid = blockIdx.x;
  const int ig = bid >> 4, jg = bid & 15;   // batch-group, col-group
  const int b0 = ig * 8, c0 = jg * 16;

  float* a_glob = ws + OFF_A;
  float* r_glob = ws + OFF_R;
  float* r_hist = ws + OFF_RH;
  float* o_hist = ws + OFF_OH;
  float* c_buf  = ws + OFF_C;
  float* mu_buf = ws + OFF_MU;
  int*   ctr    = (int*)(ws + OFF_CTR);

  // ---- one-time LDS setup ----
  for (int idx = tid; idx < 256 * 16; idx += 256) {
    int k = idx >> 4, c = idx & 15;
    Wa_l [k][c] = W_a [k * HH + c0 + c];
    Wra_l[k][c] = W_ra[k * HH + c0 + c];
    War_l[k][c] = W_ar[k * HH + c0 + c];
    Wro_l[k][c] = W_ro[k * HH + c0 + c];
    Wao_l[k][c] = W_ao[k * HH + c0 + c];
  }
  for (int idx = tid; idx < 256 * 10; idx += 256) {
    (&aST[0][0])[idx] = 0.f; (&rST[0][0])[idx] = 0.f;    // state(-1) = 0
  }
  if (tid < 48)  { Wma_l[tid >> 4][tid & 15] = W_ma[(tid >> 4) * HH + c0 + (tid & 15)]; }
  if (tid < 32)  { Wsr_l[tid >> 4][tid & 15] = W_sr[(tid >> 4) * HH + c0 + (tid & 15)]; }
  if (tid < 160) { Wy_l[tid / 10][tid % 10] = W_y[(c0 + tid / 10) * 10 + tid % 10]; }
  if (tid < 16)  { g_l[tid] = gvec[c0 + tid]; b_l[tid] = bvec[c0 + tid]; }
  if (tid < 64)  { lam_pow[tid] = powf(0.95f, (float)tid); }
  __syncthreads();

  int bar = 0;
  for (int t = 0; ; ++t) {
    // ================= PHASE X =================
    // X0: finish step t-1:  o = relu(g*(o_pre - mu) + b)
    if (t >= 1 && tid < 128) {
      int b = tid >> 4, c = tid & 15;
      float mu = mu_buf[(t - 1) * HH + c0 + c] * (1.0f / 128.0f);
      float v = fmaxf(g_l[c] * (ops[b][c] - mu) + b_l[c], 0.f);
      o_tile[b][c] = v;
      if (t - 1 <= 32) o_hist[((t - 1) * BB + b0 + b) * HH + c0 + c] = v;
    }
    __syncthreads();
    // y(t-1) partials for decision window (steps 56..63)
    if (t >= 57 && tid < 80) {
      int b = tid / 10, n = tid % 10;
      float acc = 0.f;
      #pragma unroll
      for (int c = 0; c < 16; ++c) acc += o_tile[b][c] * Wy_l[c][n];
      atomicAdd(&out[(t - 1 - 56) * (BB * 10) + (b0 + b) * 10 + n], acc);
    }
    if (t == NSTEPS) break;

    if (tid < 40) { x_l[tid / 5][tid % 5] = x_in[(t * BB + b0 + tid / 5) * 5 + tid % 5]; }

    // k-loops over state(t-1) (already staged in aST/rST by Y(t-1); zeros at t=0)
    if (tid < 128) {
      // a_new partial: a@W_a + r@W_ra   (8 batches x 4 cols per thread, k-split 32)
      int cg = tid & 3, ks = tid >> 2;
      float acc[8][4] = {};
      #pragma unroll
      for (int kk = 0; kk < 8; ++kk) {
        int k = ks + (kk << 5);
        float av[8], rv[8];
        #pragma unroll
        for (int b = 0; b < 8; ++b) { av[b] = aST[k][b]; rv[b] = rST[k][b]; }
        float wa[4], wr[4];
        #pragma unroll
        for (int c = 0; c < 4; ++c) { wa[c] = Wa_l[k][cg * 4 + c]; wr[c] = Wra_l[k][cg * 4 + c]; }
        #pragma unroll
        for (int b = 0; b < 8; ++b)
          #pragma unroll
          for (int c = 0; c < 4; ++c)
            acc[b][c] += av[b] * wa[c] + rv[b] * wr[c];
      }
      #pragma unroll
      for (int b = 0; b < 8; ++b)
        #pragma unroll
        for (int c = 0; c < 4; ++c)
          P[b * 16 + cg * 4 + c][ks] = acc[b][c];
    } else {
      // r_new partial: a_prev@W_ar
      int tt = tid - 128;
      int cg = tt & 3, ks = tt >> 2;
      float acc[8][4] = {};
      #pragma unroll
      for (int kk = 0; kk < 8; ++kk) {
        int k = ks + (kk << 5);
        float av[8];
        #pragma unroll
        for (int b = 0; b < 8; ++b) av[b] = aST[k][b];
        float wv[4];
        #pragma unroll
        for (int c = 0; c < 4; ++c) wv[c] = War_l[k][cg * 4 + c];
        #pragma unroll
        for (int b = 0; b < 8; ++b)
          #pragma unroll
          for (int c = 0; c < 4; ++c)
            acc[b][c] += av[b] * wv[c];
      }
      #pragma unroll
      for (int b = 0; b < 8; ++b)
        #pragma unroll
        for (int c = 0; c < 4; ++c)
          P[128 + b * 16 + cg * 4 + c][ks] = acc[b][c];
    }
    __syncthreads();
    // combine partials + x-terms, relu, write state(t)
    {
      int o = tid & 127;
      int b = o >> 4, c = o & 15;
      float s = 0.f;
      #pragma unroll
      for (int ks = 0; ks < 32; ++ks) s += P[tid][ks];
      if (tid < 128) {
        float xa = x_l[b][2] * Wma_l[0][c] + x_l[b][3] * Wma_l[1][c] + x_l[b][4] * Wma_l[2][c];
        float v = fmaxf(s + xa, 0.f);
        a_glob[(t & 1) * BB * HH + (b0 + b) * HH + c0 + c] = v;
      } else {
        float xr = x_l[b][0] * Wsr_l[0][c] + x_l[b][1] * Wsr_l[1][c];
        float v = fmaxf(s + xr, 0.f);
        r_glob[(t & 1) * BB * HH + (b0 + b) * HH + c0 + c] = v;
        r_tile[b][c] = v;
        if (t <= 32) r_hist[(t * BB + b0 + b) * HH + c0 + c] = v;
      }
    }
    __syncthreads();
    // dot partials c_s[b] = <r_t[b,:], o_s[b,:]> over this block's 16-col slice
    {
      int ns = t < NSLOT ? t : NSLOT;   // s in [0, min(t-1,32)]
      for (int sb = tid; sb < ns * 8; sb += 256) {
        int s = sb >> 3, b = sb & 7;
        const float* oh = &o_hist[(s * BB + b0 + b) * HH + c0];
        float acc = 0.f;
        #pragma unroll
        for (int c = 0; c < 16; ++c) acc += r_tile[b][c] * oh[c];
        atomicAdd(&c_buf[(t * NSLOT + s) * BB + b0 + b], acc);
      }
    }
    grid_barrier(ctr, bar++);   // B1: state(t) + c partials visible

    // ================= PHASE Y =================
    // stage state(t) transposed
    for (int idx = tid; idx < 2048; idx += 256) {
      int b = idx >> 8, k = idx & 255;
      aST[k][b] = a_glob[(t & 1) * BB * HH + (b0 + b) * HH + k];
      rST[k][b] = r_glob[(t & 1) * BB * HH + (b0 + b) * HH + k];
    }
    __syncthreads();
    if (tid < 128) {
      // o_pre partial: r@W_ro + a@W_ao
      int cg = tid & 3, ks = tid >> 2;
      float acc[8][4] = {};
      #pragma unroll
      for (int kk = 0; kk < 8; ++kk) {
        int k = ks + (kk << 5);
        float av[8], rv[8];
        #pragma unroll
        for (int b = 0; b < 8; ++b) { av[b] = aST[k][b]; rv[b] = rST[k][b]; }
        float wo[4], wa2[4];
        #pragma unroll
        for (int c = 0; c < 4; ++c) { wo[c] = Wro_l[k][cg * 4 + c]; wa2[c] = Wao_l[k][cg * 4 + c]; }
        #pragma unroll
        for (int b = 0; b < 8; ++b)
          #pragma unroll
          for (int c = 0; c < 4; ++c)
            acc[b][c] += rv[b] * wo[c] + av[b] * wa2[c];
      }
      #pragma unroll
      for (int b = 0; b < 8; ++b)
        #pragma unroll
        for (int c = 0; c < 4; ++c)
          P[b * 16 + cg * 4 + c][ks] = acc[b][c];
    } else {
      // rank-33 readout apply: sum_s lam^(t-1-s)*eta * c_s[b] * r_s[b,c]
      int o = tid - 128;
      int b = o >> 4, c = o & 15;
      float acc = 0.f;
      int ns = t < NSLOT ? t : NSLOT;
      for (int s = 0; s < ns; ++s) {
        float cb = c_buf[(t * NSLOT + s) * BB + b0 + b];
        float w = lam_pow[t - 1 - s] * 0.5f;
        acc += w * cb * r_hist[(s * BB + b0 + b) * HH + c0 + c];
      }
      apply_l[o] = acc;
    }
    __syncthreads();
    if (tid < 128) {
      int b = tid >> 4, c = tid & 15;
      float s = apply_l[tid];
      #pragma unroll
      for (int ks = 0; ks < 32; ++ks) s += P[tid][ks];
      ops[b][c] = s;   // raw o_pre, mean/relu applied in X(t+1)
    }
    __syncthreads();
    if (tid < 16) {
      float m = 0.f;
      #pragma unroll
      for (int b = 0; b < 8; ++b) m += ops[b][tid];
      atomicAdd(&mu_buf[t * HH + c0 + tid], m);
    }
    grid_barrier(ctr, bar++);   // B2: mu(t) partials visible
  }
}

extern "C" void kernel_launch(void* const* d_in, const int* in_sizes, int n_in,
                              void* d_out, int out_size, void* d_ws, size_t ws_size,
                              hipStream_t stream) {
  if (ws_size < (size_t)WS_FLOATS * 4) return;   // need ~10.3 MB scratch
  const float* x_in = (const float*)d_in[0];
  const float* W_sr = (const float*)d_in[1];
  const float* W_ma = (const float*)d_in[2];
  const float* W_ro = (const float*)d_in[3];
  const float* W_ao = (const float*)d_in[4];
  const float* W_ar = (const float*)d_in[5];
  const float* W_ra = (const float*)d_in[6];
  const float* W_a  = (const float*)d_in[7];
  const float* W_y  = (const float*)d_in[8];
  const float* g    = (const float*)d_in[9];
  const float* b    = (const float*)d_in[10];
  float* out = (float*)d_out;
  float* ws  = (float*)d_ws;

  hipLaunchKernelGGL(smn_init, dim3(256), dim3(256), 0, stream, ws, out);
  hipLaunchKernelGGL(smn_main, dim3(256), dim3(256), 0, stream,
                     x_in, W_sr, W_ma, W_ro, W_ao, W_ar, W_ra, W_a, W_y, g, b,
                     out, ws);
}

// Round 2
// 1330.036 us; speedup vs baseline: 3.6972x; 3.6972x over previous
//
#include <hip/hip_runtime.h>

// SimpleMemoryNetwork: T=64,B=128,H=256,NI=2,NO=10, lambda=.95, eta=.5, sample=32, decision=8
// Low-rank fast-weight reformulation: A(tau) = sum_{s<=min(tau,32)} lam^(tau-s)*eta*o_s (x) r_s
// readout_t[b,:] = sum_s lam^(t-1-s)*eta*<r_t[b],o_s[b]> * r_s[b,:]
//
// Persistent cooperative kernel: 256 blocks (16 batch-groups x 16 col-groups), 256 thr.
// R1 changes vs R0: no threadfence/acquire (no buffer_wbl2/buffer_inv per barrier);
// all cross-block data moves via agent-scope atomic (sc0 sc1 bypass) load/store;
// barriers are 16-block group barriers (B1: row=batch-group, B2: col=col-group);
// c_buf staged to LDS before apply loop; r_hist lives ONLY in LDS.

#define NSTEPS 64
#define BB 128
#define HH 256
#define NSLOT 33

// workspace layout (float offsets)
#define OFF_A   0u          // a_glob[2][128][256]
#define OFF_R   65536u      // r_glob[2][128][256]
#define OFF_OH  131072u     // o_hist[33][128][256]
#define OFF_C   1212416u    // c_buf[64][33][128]
#define OFF_MU  1482752u    // mu_buf[64][256]
#define OFF_CTR 1499136u    // barrier counters (2048 ints: [64][16] B1, [64][16] B2)
#define WS_FLOATS 1501184u

#define AGENT __HIP_MEMORY_SCOPE_AGENT
#define RLX   __ATOMIC_RELAXED

__device__ __forceinline__ float gload(const float* p) {
  return __hip_atomic_load(p, RLX, AGENT);          // global_load ... sc0 sc1 (L3-fresh)
}
__device__ __forceinline__ void gstore(float* p, float v) {
  __hip_atomic_store(p, v, RLX, AGENT);             // global_store ... sc0 sc1
}

__global__ __launch_bounds__(256) void smn_init(float* __restrict__ ws,
                                                float* __restrict__ out) {
  unsigned i = blockIdx.x * 256u + threadIdx.x;
  unsigned stride = gridDim.x * 256u;
  for (unsigned k = i; k < 288768u; k += stride) ws[OFF_C + k] = 0.f;  // c_buf+mu+ctr
  for (unsigned k = i; k < 10240u; k += stride) out[k] = 0.f;          // output
}

// 16-block group barrier. No cache maintenance: data travels via sc-bypass atomics,
// __syncthreads drains each wave's vmcnt (stores acked at coherence point) before add.
__device__ __forceinline__ void group_barrier(int* __restrict__ c) {
  __syncthreads();
  if (threadIdx.x == 0) {
    __hip_atomic_fetch_add(c, 1, RLX, AGENT);
    while (__hip_atomic_load(c, RLX, AGENT) < 16) {
      __builtin_amdgcn_s_sleep(1);
    }
  }
  __syncthreads();
}

__global__ __launch_bounds__(256) void smn_main(
    const float* __restrict__ x_in, const float* __restrict__ W_sr,
    const float* __restrict__ W_ma, const float* __restrict__ W_ro,
    const float* __restrict__ W_ao, const float* __restrict__ W_ar,
    const float* __restrict__ W_ra, const float* __restrict__ W_a,
    const float* __restrict__ W_y,  const float* __restrict__ gvec,
    const float* __restrict__ bvec, float* __restrict__ out,
    float* __restrict__ ws)
{
  // persistent weight column-slices (pad 17 breaks bank conflicts)
  __shared__ float Wa_l[256][17], Wra_l[256][17], War_l[256][17];
  __shared__ float Wro_l[256][17], Wao_l[256][17];
  __shared__ float aST[256][9], rST[256][9];     // state(t) transposed, rows=k, cols=8 batches
  __shared__ float P[256][33];                   // k-split partials
  __shared__ float r_hist_l[33][8][17];          // block-local r history slice (LDS only)
  __shared__ float c_l[33][8];                   // staged dot coefficients
  __shared__ float apply_l[128];
  __shared__ float ops[8][17], o_tile[8][17], r_tile[8][17];
  __shared__ float x_l[8][5];
  __shared__ float Wma_l[3][16], Wsr_l[2][16], Wy_l[16][10];
  __shared__ float g_l[16], b_l[16], lam_pow[64];

  const int tid = threadIdx.x;
  const int bid = blockIdx.x;
  const int ig = bid >> 4, jg = bid & 15;   // batch-group, col-group
  const int b0 = ig * 8, c0 = jg * 16;

  float* a_glob = ws + OFF_A;
  float* r_glob = ws + OFF_R;
  float* o_hist = ws + OFF_OH;
  float* c_buf  = ws + OFF_C;
  float* mu_buf = ws + OFF_MU;
  int*   ctr    = (int*)(ws + OFF_CTR);
  int*   ctr1   = ctr;          // [64][16] indexed [t][ig]
  int*   ctr2   = ctr + 1024;   // [64][16] indexed [t][jg]

  // ---- one-time LDS setup ----
  for (int idx = tid; idx < 256 * 16; idx += 256) {
    int k = idx >> 4, c = idx & 15;
    Wa_l [k][c] = W_a [k * HH + c0 + c];
    Wra_l[k][c] = W_ra[k * HH + c0 + c];
    War_l[k][c] = W_ar[k * HH + c0 + c];
    Wro_l[k][c] = W_ro[k * HH + c0 + c];
    Wao_l[k][c] = W_ao[k * HH + c0 + c];
  }
  for (int idx = tid; idx < 256 * 9; idx += 256) {
    (&aST[0][0])[idx] = 0.f; (&rST[0][0])[idx] = 0.f;    // state(-1) = 0
  }
  if (tid < 48)  { Wma_l[tid >> 4][tid & 15] = W_ma[(tid >> 4) * HH + c0 + (tid & 15)]; }
  if (tid < 32)  { Wsr_l[tid >> 4][tid & 15] = W_sr[(tid >> 4) * HH + c0 + (tid & 15)]; }
  if (tid < 160) { Wy_l[tid / 10][tid % 10] = W_y[(c0 + tid / 10) * 10 + tid % 10]; }
  if (tid < 16)  { g_l[tid] = gvec[c0 + tid]; b_l[tid] = bvec[c0 + tid]; }
  if (tid < 64)  { lam_pow[tid] = powf(0.95f, (float)tid); }
  __syncthreads();

  for (int t = 0; ; ++t) {
    // ================= PHASE X =================
    // X0: finish step t-1:  o = relu(g*(o_pre - mu) + b)
    if (t >= 1 && tid < 128) {
      int b = tid >> 4, c = tid & 15;
      float mu = gload(&mu_buf[(t - 1) * HH + c0 + c]) * (1.0f / 128.0f);
      float v = fmaxf(g_l[c] * (ops[b][c] - mu) + b_l[c], 0.f);
      o_tile[b][c] = v;
      if (t - 1 <= 32) o_hist[((t - 1) * BB + b0 + b) * HH + c0 + c] = v;  // block-local
    }
    __syncthreads();
    // y(t-1) partials for decision window (steps 56..63)
    if (t >= 57 && tid < 80) {
      int b = tid / 10, n = tid % 10;
      float acc = 0.f;
      #pragma unroll
      for (int c = 0; c < 16; ++c) acc += o_tile[b][c] * Wy_l[c][n];
      atomicAdd(&out[(t - 1 - 56) * (BB * 10) + (b0 + b) * 10 + n], acc);
    }
    if (t == NSTEPS) break;

    if (tid < 40) { x_l[tid / 5][tid % 5] = x_in[(t * BB + b0 + tid / 5) * 5 + tid % 5]; }

    // k-loops over state(t-1) (already staged in aST/rST by Y(t-1); zeros at t=0)
    if (tid < 128) {
      // a_new partial: a@W_a + r@W_ra   (8 batches x 4 cols per thread, k-split 32)
      int cg = tid & 3, ks = tid >> 2;
      float acc[8][4] = {};
      #pragma unroll
      for (int kk = 0; kk < 8; ++kk) {
        int k = ks + (kk << 5);
        float av[8], rv[8];
        #pragma unroll
        for (int b = 0; b < 8; ++b) { av[b] = aST[k][b]; rv[b] = rST[k][b]; }
        float wa[4], wr[4];
        #pragma unroll
        for (int c = 0; c < 4; ++c) { wa[c] = Wa_l[k][cg * 4 + c]; wr[c] = Wra_l[k][cg * 4 + c]; }
        #pragma unroll
        for (int b = 0; b < 8; ++b)
          #pragma unroll
          for (int c = 0; c < 4; ++c)
            acc[b][c] += av[b] * wa[c] + rv[b] * wr[c];
      }
      #pragma unroll
      for (int b = 0; b < 8; ++b)
        #pragma unroll
        for (int c = 0; c < 4; ++c)
          P[b * 16 + cg * 4 + c][ks] = acc[b][c];
    } else {
      // r_new partial: a_prev@W_ar
      int tt = tid - 128;
      int cg = tt & 3, ks = tt >> 2;
      float acc[8][4] = {};
      #pragma unroll
      for (int kk = 0; kk < 8; ++kk) {
        int k = ks + (kk << 5);
        float av[8];
        #pragma unroll
        for (int b = 0; b < 8; ++b) av[b] = aST[k][b];
        float wv[4];
        #pragma unroll
        for (int c = 0; c < 4; ++c) wv[c] = War_l[k][cg * 4 + c];
        #pragma unroll
        for (int b = 0; b < 8; ++b)
          #pragma unroll
          for (int c = 0; c < 4; ++c)
            acc[b][c] += av[b] * wv[c];
      }
      #pragma unroll
      for (int b = 0; b < 8; ++b)
        #pragma unroll
        for (int c = 0; c < 4; ++c)
          P[128 + b * 16 + cg * 4 + c][ks] = acc[b][c];
    }
    __syncthreads();
    // combine partials + x-terms, relu, write state(t) (bypass stores: cross-block)
    {
      int o = tid & 127;
      int b = o >> 4, c = o & 15;
      float s = 0.f;
      #pragma unroll
      for (int ks = 0; ks < 32; ++ks) s += P[tid][ks];
      if (tid < 128) {
        float xa = x_l[b][2] * Wma_l[0][c] + x_l[b][3] * Wma_l[1][c] + x_l[b][4] * Wma_l[2][c];
        float v = fmaxf(s + xa, 0.f);
        gstore(&a_glob[(t & 1) * BB * HH + (b0 + b) * HH + c0 + c], v);
      } else {
        float xr = x_l[b][0] * Wsr_l[0][c] + x_l[b][1] * Wsr_l[1][c];
        float v = fmaxf(s + xr, 0.f);
        gstore(&r_glob[(t & 1) * BB * HH + (b0 + b) * HH + c0 + c], v);
        r_tile[b][c] = v;
        if (t <= 32) r_hist_l[t][b][c] = v;
      }
    }
    __syncthreads();
    // dot partials c_s[b] = <r_t[b,:], o_s[b,:]> over this block's 16-col slice
    {
      int ns = t < NSLOT ? t : NSLOT;   // s in [0, min(t-1,32)]
      for (int sb = tid; sb < ns * 8; sb += 256) {
        int s = sb >> 3, b = sb & 7;
        const float* oh = &o_hist[(s * BB + b0 + b) * HH + c0];
        float acc = 0.f;
        #pragma unroll
        for (int c = 0; c < 16; ++c) acc += r_tile[b][c] * oh[c];
        atomicAdd(&c_buf[(t * NSLOT + s) * BB + b0 + b], acc);
      }
    }
    group_barrier(&ctr1[t * 16 + ig]);   // B1: row sync — state(t) + c partials at L3

    // ================= PHASE Y =================
    // stage state(t) transposed (bypass loads: written by row peers) + c coefficients
    for (int idx = tid; idx < 2048; idx += 256) {
      int b = idx >> 8, k = idx & 255;
      aST[k][b] = gload(&a_glob[(t & 1) * BB * HH + (b0 + b) * HH + k]);
      rST[k][b] = gload(&r_glob[(t & 1) * BB * HH + (b0 + b) * HH + k]);
    }
    {
      int ns = t < NSLOT ? t : NSLOT;
      for (int idx = tid; idx < ns * 8; idx += 256) {
        int s = idx >> 3, b = idx & 7;
        c_l[s][b] = gload(&c_buf[(t * NSLOT + s) * BB + b0 + b]);
      }
    }
    __syncthreads();
    if (tid < 128) {
      // o_pre partial: r@W_ro + a@W_ao
      int cg = tid & 3, ks = tid >> 2;
      float acc[8][4] = {};
      #pragma unroll
      for (int kk = 0; kk < 8; ++kk) {
        int k = ks + (kk << 5);
        float av[8], rv[8];
        #pragma unroll
        for (int b = 0; b < 8; ++b) { av[b] = aST[k][b]; rv[b] = rST[k][b]; }
        float wo[4], wa2[4];
        #pragma unroll
        for (int c = 0; c < 4; ++c) { wo[c] = Wro_l[k][cg * 4 + c]; wa2[c] = Wao_l[k][cg * 4 + c]; }
        #pragma unroll
        for (int b = 0; b < 8; ++b)
          #pragma unroll
          for (int c = 0; c < 4; ++c)
            acc[b][c] += rv[b] * wo[c] + av[b] * wa2[c];
      }
      #pragma unroll
      for (int b = 0; b < 8; ++b)
        #pragma unroll
        for (int c = 0; c < 4; ++c)
          P[b * 16 + cg * 4 + c][ks] = acc[b][c];
    } else {
      // rank-33 readout apply: sum_s lam^(t-1-s)*eta * c_s[b] * r_s[b,c]  (all LDS)
      int o = tid - 128;
      int b = o >> 4, c = o & 15;
      float acc = 0.f;
      int ns = t < NSLOT ? t : NSLOT;
      for (int s = 0; s < ns; ++s) {
        float w = lam_pow[t - 1 - s] * 0.5f;
        acc += w * c_l[s][b] * r_hist_l[s][b][c];
      }
      apply_l[o] = acc;
    }
    __syncthreads();
    if (tid < 128) {
      int b = tid >> 4, c = tid & 15;
      float s = apply_l[tid];
      #pragma unroll
      for (int ks = 0; ks < 32; ++ks) s += P[tid][ks];
      ops[b][c] = s;   // raw o_pre, mean/relu applied in X(t+1)
    }
    __syncthreads();
    if (tid < 16) {
      float m = 0.f;
      #pragma unroll
      for (int b = 0; b < 8; ++b) m += ops[b][tid];
      atomicAdd(&mu_buf[t * HH + c0 + tid], m);
    }
    group_barrier(&ctr2[t * 16 + jg]);   // B2: col sync — mu(t) partials at L3
  }
}

extern "C" void kernel_launch(void* const* d_in, const int* in_sizes, int n_in,
                              void* d_out, int out_size, void* d_ws, size_t ws_size,
                              hipStream_t stream) {
  if (ws_size < (size_t)WS_FLOATS * 4) return;   // need ~6 MB scratch
  const float* x_in = (const float*)d_in[0];
  const float* W_sr = (const float*)d_in[1];
  const float* W_ma = (const float*)d_in[2];
  const float* W_ro = (const float*)d_in[3];
  const float* W_ao = (const float*)d_in[4];
  const float* W_ar = (const float*)d_in[5];
  const float* W_ra = (const float*)d_in[6];
  const float* W_a  = (const float*)d_in[7];
  const float* W_y  = (const float*)d_in[8];
  const float* g    = (const float*)d_in[9];
  const float* b    = (const float*)d_in[10];
  float* out = (float*)d_out;
  float* ws  = (float*)d_ws;

  hipLaunchKernelGGL(smn_init, dim3(256), dim3(256), 0, stream, ws, out);
  hipLaunchKernelGGL(smn_main, dim3(256), dim3(256), 0, stream,
                     x_in, W_sr, W_ma, W_ro, W_ao, W_ar, W_ra, W_a, W_y, g, b,
                     out, ws);
}

// Round 3
// 842.633 us; speedup vs baseline: 5.8357x; 1.5784x over previous
//
#include <hip/hip_runtime.h>

// SimpleMemoryNetwork: T=64,B=128,H=256,NI=2,NO=10, lambda=.95, eta=.5, sample=32, decision=8
// Low-rank fast-weight reformulation: A(tau) = sum_{s<=min(tau,32)} lam^(tau-s)*eta*o_s (x) r_s
// readout_t[b,:] = sum_s lam^(t-1-s)*eta*<r_t[b],o_s[b]> * r_s[b,:]
//
// 256 blocks (16 batch-groups x 16 col-groups) x 256 thr, weights LDS-resident.
// R2 vs R1: flag-based barriers (no atomic contention, parallel per-peer spin);
// software-pipelined schedule hides barrier-2 behind the a/r matmuls; dots for
// old slots run pre-barrier; float4 o_hist loads.

#define NSTEPS 64
#define BB 128
#define HH 256
#define NSLOT 33

// workspace layout (float offsets)
#define OFF_A    0u          // a_glob[2][128][256]
#define OFF_R    65536u      // r_glob[2][128][256]
#define OFF_OH   131072u     // o_hist[33][128][256] (block-local slices)
#define OFF_C    1212416u    // c_buf[64][33][128]
#define OFF_MU   1482752u    // mu_buf[64][256]
#define OFF_F1   1499136u    // flags1[256]  (row barrier: state+c published)
#define OFF_F2   1499392u    // flags2[256]  (col barrier: mu published)
#define WS_FLOATS 1499648u

#define AGENT __HIP_MEMORY_SCOPE_AGENT
#define RLX   __ATOMIC_RELAXED

__device__ __forceinline__ float gload(const float* p) {
  return __hip_atomic_load(p, RLX, AGENT);          // sc0 sc1 bypass (L3-fresh)
}
__device__ __forceinline__ void gstore(float* p, float v) {
  __hip_atomic_store(p, v, RLX, AGENT);
}
__device__ __forceinline__ void gstore_i(int* p, int v) {
  __hip_atomic_store(p, v, RLX, AGENT);
}
__device__ __forceinline__ void spin_ge(const int* f, int target) {
  while (__hip_atomic_load(f, RLX, AGENT) < target) __builtin_amdgcn_s_sleep(1);
}

__global__ __launch_bounds__(256) void smn_init(float* __restrict__ ws,
                                                float* __restrict__ out) {
  unsigned i = blockIdx.x * 256u + threadIdx.x;
  unsigned stride = gridDim.x * 256u;
  for (unsigned k = i; k < 287232u; k += stride) ws[OFF_C + k] = 0.f;  // c_buf+mu+flags
  for (unsigned k = i; k < 10240u; k += stride) out[k] = 0.f;          // output
}

__global__ __launch_bounds__(256) void smn_main(
    const float* __restrict__ x_in, const float* __restrict__ W_sr,
    const float* __restrict__ W_ma, const float* __restrict__ W_ro,
    const float* __restrict__ W_ao, const float* __restrict__ W_ar,
    const float* __restrict__ W_ra, const float* __restrict__ W_a,
    const float* __restrict__ W_y,  const float* __restrict__ gvec,
    const float* __restrict__ bvec, float* __restrict__ out,
    float* __restrict__ ws)
{
  __shared__ float Wa_l[256][17], Wra_l[256][17], War_l[256][17];
  __shared__ float Wro_l[256][17], Wao_l[256][17];
  __shared__ float aST[256][9], rST[256][9];     // state(t) transposed
  __shared__ float P[256][33];                   // k-split partials
  __shared__ float r_hist_l[33][8][17];          // block-local r history (LDS only)
  __shared__ float c_l[33][8];
  __shared__ float apply_l[128];
  __shared__ float ops[8][17], o_tile[8][17], r_tile[8][17];
  __shared__ float x_l[8][5];
  __shared__ float Wma_l[3][16], Wsr_l[2][16], Wy_l[16][10];
  __shared__ float g_l[16], b_l[16], lam_pow[64];

  const int tid = threadIdx.x;
  const int bid = blockIdx.x;
  const int ig = bid >> 4, jg = bid & 15;
  const int b0 = ig * 8, c0 = jg * 16;

  float* a_glob = ws + OFF_A;
  float* r_glob = ws + OFF_R;
  float* o_hist = ws + OFF_OH;
  float* c_buf  = ws + OFF_C;
  float* mu_buf = ws + OFF_MU;
  int*   flags1 = (int*)(ws + OFF_F1);
  int*   flags2 = (int*)(ws + OFF_F2);

  // ---- one-time LDS setup ----
  for (int idx = tid; idx < 256 * 16; idx += 256) {
    int k = idx >> 4, c = idx & 15;
    Wa_l [k][c] = W_a [k * HH + c0 + c];
    Wra_l[k][c] = W_ra[k * HH + c0 + c];
    War_l[k][c] = W_ar[k * HH + c0 + c];
    Wro_l[k][c] = W_ro[k * HH + c0 + c];
    Wao_l[k][c] = W_ao[k * HH + c0 + c];
  }
  for (int idx = tid; idx < 256 * 9; idx += 256) {
    (&aST[0][0])[idx] = 0.f; (&rST[0][0])[idx] = 0.f;    // state(-1) = 0
  }
  if (tid < 48)  { Wma_l[tid >> 4][tid & 15] = W_ma[(tid >> 4) * HH + c0 + (tid & 15)]; }
  if (tid < 32)  { Wsr_l[tid >> 4][tid & 15] = W_sr[(tid >> 4) * HH + c0 + (tid & 15)]; }
  if (tid < 160) { Wy_l[tid / 10][tid % 10] = W_y[(c0 + tid / 10) * 10 + tid % 10]; }
  if (tid < 16)  { g_l[tid] = gvec[c0 + tid]; b_l[tid] = bvec[c0 + tid]; }
  if (tid < 64)  { lam_pow[tid] = powf(0.95f, (float)tid); }
  __syncthreads();

  for (int t = 0; t <= NSTEPS; ++t) {
    if (t < NSTEPS) {
      // ---- (A) a/r(t) k-split partials from staged state(t-1) ----
      if (tid < 40) { x_l[tid / 5][tid % 5] = x_in[(t * BB + b0 + tid / 5) * 5 + tid % 5]; }
      if (tid < 128) {
        int cg = tid & 3, ks = tid >> 2;
        float acc[8][4] = {};
        #pragma unroll
        for (int kk = 0; kk < 8; ++kk) {
          int k = ks + (kk << 5);
          float av[8], rv[8];
          #pragma unroll
          for (int b = 0; b < 8; ++b) { av[b] = aST[k][b]; rv[b] = rST[k][b]; }
          float wa[4], wr[4];
          #pragma unroll
          for (int c = 0; c < 4; ++c) { wa[c] = Wa_l[k][cg * 4 + c]; wr[c] = Wra_l[k][cg * 4 + c]; }
          #pragma unroll
          for (int b = 0; b < 8; ++b)
            #pragma unroll
            for (int c = 0; c < 4; ++c)
              acc[b][c] += av[b] * wa[c] + rv[b] * wr[c];
        }
        #pragma unroll
        for (int b = 0; b < 8; ++b)
          #pragma unroll
          for (int c = 0; c < 4; ++c)
            P[b * 16 + cg * 4 + c][ks] = acc[b][c];
      } else {
        int tt = tid - 128;
        int cg = tt & 3, ks = tt >> 2;
        float acc[8][4] = {};
        #pragma unroll
        for (int kk = 0; kk < 8; ++kk) {
          int k = ks + (kk << 5);
          float av[8];
          #pragma unroll
          for (int b = 0; b < 8; ++b) av[b] = aST[k][b];
          float wv[4];
          #pragma unroll
          for (int c = 0; c < 4; ++c) wv[c] = War_l[k][cg * 4 + c];
          #pragma unroll
          for (int b = 0; b < 8; ++b)
            #pragma unroll
            for (int c = 0; c < 4; ++c)
              acc[b][c] += av[b] * wv[c];
        }
        #pragma unroll
        for (int b = 0; b < 8; ++b)
          #pragma unroll
          for (int c = 0; c < 4; ++c)
            P[128 + b * 16 + cg * 4 + c][ks] = acc[b][c];
      }
      __syncthreads();
      // ---- (B) combine + relu + publish state(t); r_tile/r_hist ----
      {
        int o = tid & 127;
        int b = o >> 4, c = o & 15;
        float s = 0.f;
        #pragma unroll
        for (int ks = 0; ks < 32; ++ks) s += P[tid][ks];
        if (tid < 128) {
          float xa = x_l[b][2] * Wma_l[0][c] + x_l[b][3] * Wma_l[1][c] + x_l[b][4] * Wma_l[2][c];
          float v = fmaxf(s + xa, 0.f);
          gstore(&a_glob[(t & 1) * BB * HH + (b0 + b) * HH + c0 + c], v);
        } else {
          float xr = x_l[b][0] * Wsr_l[0][c] + x_l[b][1] * Wsr_l[1][c];
          float v = fmaxf(s + xr, 0.f);
          gstore(&r_glob[(t & 1) * BB * HH + (b0 + b) * HH + c0 + c], v);
          r_tile[b][c] = v;
          if (t <= 32) r_hist_l[t][b][c] = v;
        }
      }
      __syncthreads();
      // ---- (C) dot partials for old slots s <= t-2 (hides barrier-2) ----
      {
        int ns2 = (t >= 1) ? (t - 1 < NSLOT ? t - 1 : NSLOT) : 0;
        for (int sb = tid; sb < ns2 * 8; sb += 256) {
          int s = sb >> 3, b = sb & 7;
          const float4* oh = reinterpret_cast<const float4*>(&o_hist[(s * BB + b0 + b) * HH + c0]);
          float4 o0 = oh[0], o1 = oh[1], o2 = oh[2], o3 = oh[3];
          float acc = r_tile[b][0]  * o0.x + r_tile[b][1]  * o0.y + r_tile[b][2]  * o0.z + r_tile[b][3]  * o0.w
                    + r_tile[b][4]  * o1.x + r_tile[b][5]  * o1.y + r_tile[b][6]  * o1.z + r_tile[b][7]  * o1.w
                    + r_tile[b][8]  * o2.x + r_tile[b][9]  * o2.y + r_tile[b][10] * o2.z + r_tile[b][11] * o2.w
                    + r_tile[b][12] * o3.x + r_tile[b][13] * o3.y + r_tile[b][14] * o3.z + r_tile[b][15] * o3.w;
          atomicAdd(&c_buf[(t * NSLOT + s) * BB + b0 + b], acc);
        }
      }
    }
    if (t >= 1) {
      // ---- (D) barrier-2 wait: col peers' mu(t-1) published ----
      if (tid < 16) spin_ge(&flags2[tid * 16 + jg], t);
      __syncthreads();
      // ---- (E) finish o(t-1); y; dot slot t-1 ----
      if (tid < 128) {
        int b = tid >> 4, c = tid & 15;
        float mu = gload(&mu_buf[(t - 1) * HH + c0 + c]) * (1.0f / 128.0f);
        float v = fmaxf(g_l[c] * (ops[b][c] - mu) + b_l[c], 0.f);
        o_tile[b][c] = v;
        if (t - 1 <= 32) o_hist[((t - 1) * BB + b0 + b) * HH + c0 + c] = v;
      }
      __syncthreads();
      if (t >= 57 && tid < 80) {
        int b = tid / 10, n = tid % 10;
        float acc = 0.f;
        #pragma unroll
        for (int c = 0; c < 16; ++c) acc += o_tile[b][c] * Wy_l[c][n];
        atomicAdd(&out[(t - 1 - 56) * (BB * 10) + (b0 + b) * 10 + n], acc);
      }
      if (t <= 33 && t < NSTEPS && tid < 8) {    // dot slot s = t-1 (needs o(t-1))
        int b = tid;
        float acc = 0.f;
        #pragma unroll
        for (int c = 0; c < 16; ++c) acc += r_tile[b][c] * o_tile[b][c];
        atomicAdd(&c_buf[(t * NSLOT + (t - 1)) * BB + b0 + b], acc);
      }
    }
    if (t == NSTEPS) break;
    // ---- (F) arrive barrier-1: state(t)+c(t) drained, then flag ----
    __syncthreads();
    if (tid == 0) gstore_i(&flags1[bid], t + 1);
    // ---- (G) barrier-1 wait + gather state(t) + c coefficients ----
    if (tid < 16) spin_ge(&flags1[ig * 16 + tid], t + 1);
    __syncthreads();
    for (int idx = tid; idx < 2048; idx += 256) {
      int b = idx >> 8, k = idx & 255;
      aST[k][b] = gload(&a_glob[(t & 1) * BB * HH + (b0 + b) * HH + k]);
      rST[k][b] = gload(&r_glob[(t & 1) * BB * HH + (b0 + b) * HH + k]);
    }
    {
      int ns = t < NSLOT ? t : NSLOT;
      for (int idx = tid; idx < ns * 8; idx += 256) {
        int s = idx >> 3, b = idx & 7;
        c_l[s][b] = gload(&c_buf[(t * NSLOT + s) * BB + b0 + b]);
      }
    }
    __syncthreads();
    // ---- (H) o_pre(t) partials + rank-33 apply ----
    if (tid < 128) {
      int cg = tid & 3, ks = tid >> 2;
      float acc[8][4] = {};
      #pragma unroll
      for (int kk = 0; kk < 8; ++kk) {
        int k = ks + (kk << 5);
        float av[8], rv[8];
        #pragma unroll
        for (int b = 0; b < 8; ++b) { av[b] = aST[k][b]; rv[b] = rST[k][b]; }
        float wo[4], wa2[4];
        #pragma unroll
        for (int c = 0; c < 4; ++c) { wo[c] = Wro_l[k][cg * 4 + c]; wa2[c] = Wao_l[k][cg * 4 + c]; }
        #pragma unroll
        for (int b = 0; b < 8; ++b)
          #pragma unroll
          for (int c = 0; c < 4; ++c)
            acc[b][c] += rv[b] * wo[c] + av[b] * wa2[c];
      }
      #pragma unroll
      for (int b = 0; b < 8; ++b)
        #pragma unroll
        for (int c = 0; c < 4; ++c)
          P[b * 16 + cg * 4 + c][ks] = acc[b][c];
    } else {
      int o = tid - 128;
      int b = o >> 4, c = o & 15;
      float acc = 0.f;
      int ns = t < NSLOT ? t : NSLOT;
      for (int s = 0; s < ns; ++s) {
        float w = lam_pow[t - 1 - s] * 0.5f;
        acc += w * c_l[s][b] * r_hist_l[s][b][c];
      }
      apply_l[o] = acc;
    }
    __syncthreads();
    if (tid < 128) {
      int b = tid >> 4, c = tid & 15;
      float s = apply_l[tid];
      #pragma unroll
      for (int ks = 0; ks < 32; ++ks) s += P[tid][ks];
      ops[b][c] = s;
    }
    __syncthreads();
    if (tid < 16) {
      float m = 0.f;
      #pragma unroll
      for (int b = 0; b < 8; ++b) m += ops[b][tid];
      atomicAdd(&mu_buf[t * HH + c0 + tid], m);
    }
    // ---- arrive barrier-2: mu(t) drained, then flag ----
    __syncthreads();
    if (tid == 0) gstore_i(&flags2[bid], t + 1);
  }
}

extern "C" void kernel_launch(void* const* d_in, const int* in_sizes, int n_in,
                              void* d_out, int out_size, void* d_ws, size_t ws_size,
                              hipStream_t stream) {
  if (ws_size < (size_t)WS_FLOATS * 4) return;   // ~6 MB scratch
  const float* x_in = (const float*)d_in[0];
  const float* W_sr = (const float*)d_in[1];
  const float* W_ma = (const float*)d_in[2];
  const float* W_ro = (const float*)d_in[3];
  const float* W_ao = (const float*)d_in[4];
  const float* W_ar = (const float*)d_in[5];
  const float* W_ra = (const float*)d_in[6];
  const float* W_a  = (const float*)d_in[7];
  const float* W_y  = (const float*)d_in[8];
  const float* g    = (const float*)d_in[9];
  const float* b    = (const float*)d_in[10];
  float* out = (float*)d_out;
  float* ws  = (float*)d_ws;

  hipLaunchKernelGGL(smn_init, dim3(256), dim3(256), 0, stream, ws, out);
  hipLaunchKernelGGL(smn_main, dim3(256), dim3(256), 0, stream,
                     x_in, W_sr, W_ma, W_ro, W_ao, W_ar, W_ra, W_a, W_y, g, b,
                     out, ws);
}

// Round 4
// 831.643 us; speedup vs baseline: 5.9128x; 1.0132x over previous
//
#include <hip/hip_runtime.h>

// SimpleMemoryNetwork: T=64,B=128,H=256,NI=2,NO=10, lambda=.95, eta=.5, sample=32, decision=8
// Low-rank fast-weight reformulation: readout_t = sum_s lam^(t-1-s)*eta*<r_t,o_s>*r_s  (s<=min(t-1,32))
//
// R4: BARRIER-FREE dataflow. 256 blocks (16 batch-groups x 16 col-groups) x 256 thr.
// Cross-block values are self-flagging via impossible sentinels:
//   state (a,r) >= 0 (relu)  -> sentinel -1.0, packed u64 (a,r), poll sign bit
//   c partials  >= 0         -> sentinel -1.0, scalar
//   mu partials (any sign)   -> sentinel NaN 0x7FC00000, packed u64 pairs
// Slots cycle with period 5; producers re-sentinel their own words 3 steps ahead.
// Skew bounds (derived from the dependency chains) make P=5 race-free.

#define NSTEPS 64
#define BB 128
#define HH 256
#define P_SL 5

typedef unsigned long long u64;

// workspace layout (float offsets)
#define OFF_ST 0u            // st64[5][128][256] u64 (a,r) pairs          = 327680 floats
#define OFF_C  327680u       // c_parts[5][33][128][16] floats             = 337920
#define OFF_MU 665600u       // mu64[5][16][128] u64 pairs                 = 20480 floats
#define OFF_OH 686080u       // o_hist[33][16][128][16] floats (private)   = 1081344
#define WS_FLOATS 1767424u   // ~7.07 MB

#define SENT_STATE_PAIR 0xBF800000BF800000ull
#define SENT_NAN 0x7FC00000u
#define SENT_NAN_PAIR 0x7FC000007FC00000ull

#define AGENT __HIP_MEMORY_SCOPE_AGENT
#define RLX   __ATOMIC_RELAXED

__device__ __forceinline__ u64 ld64(const u64* p) { return __hip_atomic_load(p, RLX, AGENT); }
__device__ __forceinline__ void st64s(u64* p, u64 v) { __hip_atomic_store(p, v, RLX, AGENT); }
__device__ __forceinline__ float ld32f(const float* p) { return __hip_atomic_load(p, RLX, AGENT); }
__device__ __forceinline__ void st32f(float* p, float v) { __hip_atomic_store(p, v, RLX, AGENT); }
__device__ __forceinline__ u64 pack2(float lo, float hi) {
  return (u64)__float_as_uint(lo) | ((u64)__float_as_uint(hi) << 32);
}

__global__ __launch_bounds__(256) void smn_init(float* __restrict__ ws,
                                                float* __restrict__ out) {
  unsigned i = blockIdx.x * 256u + threadIdx.x;
  unsigned stride = gridDim.x * 256u;
  u64* st = (u64*)(ws + OFF_ST);
  float* cp = ws + OFF_C;
  u64* mu = (u64*)(ws + OFF_MU);
  for (unsigned k = i; k < 163840u; k += stride) st[k] = SENT_STATE_PAIR;
  for (unsigned k = i; k < 337920u; k += stride) cp[k] = -1.0f;
  for (unsigned k = i; k < 10240u;  k += stride) mu[k] = SENT_NAN_PAIR;
  for (unsigned k = i; k < 10240u;  k += stride) out[k] = 0.f;
}

__global__ __launch_bounds__(256) void smn_main(
    const float* __restrict__ x_in, const float* __restrict__ W_sr,
    const float* __restrict__ W_ma, const float* __restrict__ W_ro,
    const float* __restrict__ W_ao, const float* __restrict__ W_ar,
    const float* __restrict__ W_ra, const float* __restrict__ W_a,
    const float* __restrict__ W_y,  const float* __restrict__ gvec,
    const float* __restrict__ bvec, float* __restrict__ out,
    float* __restrict__ ws)
{
  __shared__ float Wa_l[256][17], Wra_l[256][17], War_l[256][17];
  __shared__ float Wro_l[256][17], Wao_l[256][17];
  __shared__ float aST[256][9], rST[256][9];     // state(t) transposed
  __shared__ float P[256][33];                   // k-split partials
  __shared__ float r_hist_l[33][8][16];          // block-local r history (LDS only)
  __shared__ float c_l[33][8];
  __shared__ float apply_l[128];
  __shared__ float ops[8][16], o_tile[8][16], r_tile[8][16], a_tile[8][16];
  __shared__ float x_l[8][5];
  __shared__ float Wma_l[3][16], Wsr_l[2][16], Wy_l[16][10];
  __shared__ float g_l[16], b_l[16], lam_pow[64];
  __shared__ float muP[16][16];

  const int tid = threadIdx.x;
  const int bid = blockIdx.x;
  const int ig = bid >> 4, jg = bid & 15;
  const int b0 = ig * 8, c0 = jg * 16;

  u64*   st64    = (u64*)(ws + OFF_ST);
  float* c_parts = ws + OFF_C;
  u64*   mu64    = (u64*)(ws + OFF_MU);
  float* o_hist  = ws + OFF_OH;

  // ---- one-time LDS setup ----
  for (int idx = tid; idx < 256 * 16; idx += 256) {
    int k = idx >> 4, c = idx & 15;
    Wa_l [k][c] = W_a [k * HH + c0 + c];
    Wra_l[k][c] = W_ra[k * HH + c0 + c];
    War_l[k][c] = W_ar[k * HH + c0 + c];
    Wro_l[k][c] = W_ro[k * HH + c0 + c];
    Wao_l[k][c] = W_ao[k * HH + c0 + c];
  }
  if (tid < 48)  { Wma_l[tid >> 4][tid & 15] = W_ma[(tid >> 4) * HH + c0 + (tid & 15)]; }
  if (tid < 32)  { Wsr_l[tid >> 4][tid & 15] = W_sr[(tid >> 4) * HH + c0 + (tid & 15)]; }
  if (tid < 160) { Wy_l[tid / 10][tid % 10] = W_y[(c0 + tid / 10) * 10 + tid % 10]; }
  if (tid < 16)  { g_l[tid] = gvec[c0 + tid]; b_l[tid] = bvec[c0 + tid]; }
  if (tid < 64)  { lam_pow[tid] = powf(0.95f, (float)tid); }
  if (tid < 40)  { x_l[tid / 5][tid % 5] = x_in[(b0 + tid / 5) * 5 + tid % 5]; } // x(0)
  __syncthreads();

  // ---- prologue A(0): state(0) from zero carry ----
  if (tid < 128) {
    int b = tid >> 4, c = tid & 15;
    float v = fmaxf(x_l[b][2] * Wma_l[0][c] + x_l[b][3] * Wma_l[1][c] + x_l[b][4] * Wma_l[2][c], 0.f);
    a_tile[b][c] = v;
  } else {
    int o = tid - 128; int b = o >> 4, c = o & 15;
    float v = fmaxf(x_l[b][0] * Wsr_l[0][c] + x_l[b][1] * Wsr_l[1][c], 0.f);
    r_tile[b][c] = v;
    r_hist_l[0][b][c] = v;
  }
  __syncthreads();
  if (tid < 128) {
    int b = tid >> 4, c = tid & 15;
    st64s(&st64[(0 * BB + b0 + b) * HH + c0 + c], pack2(a_tile[b][c], r_tile[b][c]));
  }

  for (int t = 0; t < NSTEPS; ++t) {
    const int inst = t % P_SL;
    // ================= G: gather state(t) + c(t) =================
    {
      u64 v[8]; int okm = 0; int base[8];
      #pragma unroll
      for (int i = 0; i < 8; ++i) {
        int idx = tid + i * 256;            // [0,2048)
        int b = idx >> 8, k = idx & 255;
        base[i] = (inst * BB + b0 + b) * HH + k;
      }
      while (okm != 255) {
        #pragma unroll
        for (int i = 0; i < 8; ++i) if (!(okm & (1 << i))) {
          v[i] = ld64(&st64[base[i]]);
          if (!(v[i] & 0x80000000ull)) okm |= 1 << i;
        }
      }
      #pragma unroll
      for (int i = 0; i < 8; ++i) {
        int idx = tid + i * 256; int b = idx >> 8, k = idx & 255;
        aST[k][b] = __uint_as_float((unsigned)v[i]);
        rST[k][b] = __uint_as_float((unsigned)(v[i] >> 32));
      }
    }
    {
      int ns = (t < 33) ? t : 33;           // slots s = 0..ns-1 (= min(t-1,32))
      for (int sb = tid; sb < ns * 8; sb += 256) {
        int s = sb >> 3, b = sb & 7;
        const float* cp = &c_parts[((inst * 33 + s) * BB + b0 + b) * 16];
        float vv[16]; unsigned om = 0;
        while (om != 0xFFFFu) {
          #pragma unroll
          for (int j = 0; j < 16; ++j) if (!(om & (1u << j))) {
            float x = ld32f(&cp[j]);
            if (!(__float_as_uint(x) >> 31)) { vv[j] = x; om |= 1u << j; }
          }
        }
        float sum = 0.f;
        #pragma unroll
        for (int j = 0; j < 16; ++j) sum += vv[j];
        c_l[s][b] = sum;
      }
    }
    __syncthreads();
    // ================= M: o_pre partials + rank apply =================
    if (tid < 128) {
      int cg = tid & 3, ks = tid >> 2;
      float acc[8][4] = {};
      #pragma unroll
      for (int kk = 0; kk < 8; ++kk) {
        int k = ks + (kk << 5);
        float av[8], rv[8];
        #pragma unroll
        for (int b = 0; b < 8; ++b) { av[b] = aST[k][b]; rv[b] = rST[k][b]; }
        float wo[4], wa2[4];
        #pragma unroll
        for (int c = 0; c < 4; ++c) { wo[c] = Wro_l[k][cg * 4 + c]; wa2[c] = Wao_l[k][cg * 4 + c]; }
        #pragma unroll
        for (int b = 0; b < 8; ++b)
          #pragma unroll
          for (int c = 0; c < 4; ++c)
            acc[b][c] += rv[b] * wo[c] + av[b] * wa2[c];
      }
      #pragma unroll
      for (int b = 0; b < 8; ++b)
        #pragma unroll
        for (int c = 0; c < 4; ++c)
          P[b * 16 + cg * 4 + c][ks] = acc[b][c];
    } else {
      int o = tid - 128; int b = o >> 4, c = o & 15;
      float acc = 0.f;
      int ns = (t < 33) ? t : 33;
      for (int s = 0; s < ns; ++s)
        acc += lam_pow[t - 1 - s] * 0.5f * c_l[s][b] * r_hist_l[s][b][c];
      apply_l[o] = acc;
    }
    __syncthreads();
    if (tid < 128) {
      float s = apply_l[tid];
      #pragma unroll
      for (int ks = 0; ks < 32; ++ks) s += P[tid][ks];
      ops[tid >> 4][tid & 15] = s;
    }
    __syncthreads();
    // ================= U: publish mu partial =================
    if (tid < 8) {
      float m0 = 0.f, m1 = 0.f;
      #pragma unroll
      for (int b = 0; b < 8; ++b) { m0 += ops[b][2 * tid]; m1 += ops[b][2 * tid + 1]; }
      st64s(&mu64[(inst * 16 + ig) * 128 + jg * 8 + tid], pack2(m0, m1));
    }
    // ================= A(t+1): a/r matmul + state publish =================
    const int tin = (t + 1) % P_SL;
    const int rin = (t + 3) % P_SL;
    if (t < NSTEPS - 1) {
      if (t + 3 <= 63 && tid < 128) {       // state slot re-sentinel (3 steps ahead)
        int b = tid >> 4, c = tid & 15;
        st64s(&st64[(rin * BB + b0 + b) * HH + c0 + c], SENT_STATE_PAIR);
      }
      if (tid < 40) { x_l[tid / 5][tid % 5] = x_in[((t + 1) * BB + b0 + tid / 5) * 5 + tid % 5]; }
      if (tid < 128) {
        int cg = tid & 3, ks = tid >> 2;
        float acc[8][4] = {};
        #pragma unroll
        for (int kk = 0; kk < 8; ++kk) {
          int k = ks + (kk << 5);
          float av[8], rv[8];
          #pragma unroll
          for (int b = 0; b < 8; ++b) { av[b] = aST[k][b]; rv[b] = rST[k][b]; }
          float wa[4], wr[4];
          #pragma unroll
          for (int c = 0; c < 4; ++c) { wa[c] = Wa_l[k][cg * 4 + c]; wr[c] = Wra_l[k][cg * 4 + c]; }
          #pragma unroll
          for (int b = 0; b < 8; ++b)
            #pragma unroll
            for (int c = 0; c < 4; ++c)
              acc[b][c] += av[b] * wa[c] + rv[b] * wr[c];
        }
        #pragma unroll
        for (int b = 0; b < 8; ++b)
          #pragma unroll
          for (int c = 0; c < 4; ++c)
            P[b * 16 + cg * 4 + c][ks] = acc[b][c];
      } else {
        int tt = tid - 128; int cg = tt & 3, ks = tt >> 2;
        float acc[8][4] = {};
        #pragma unroll
        for (int kk = 0; kk < 8; ++kk) {
          int k = ks + (kk << 5);
          float av[8];
          #pragma unroll
          for (int b = 0; b < 8; ++b) av[b] = aST[k][b];
          float wv[4];
          #pragma unroll
          for (int c = 0; c < 4; ++c) wv[c] = War_l[k][cg * 4 + c];
          #pragma unroll
          for (int b = 0; b < 8; ++b)
            #pragma unroll
            for (int c = 0; c < 4; ++c)
              acc[b][c] += av[b] * wv[c];
        }
        #pragma unroll
        for (int b = 0; b < 8; ++b)
          #pragma unroll
          for (int c = 0; c < 4; ++c)
            P[128 + b * 16 + cg * 4 + c][ks] = acc[b][c];
      }
      __syncthreads();
      {
        int o = tid & 127; int b = o >> 4, c = o & 15;
        float s = 0.f;
        #pragma unroll
        for (int ks = 0; ks < 32; ++ks) s += P[tid][ks];
        if (tid < 128) {
          float xa = x_l[b][2] * Wma_l[0][c] + x_l[b][3] * Wma_l[1][c] + x_l[b][4] * Wma_l[2][c];
          a_tile[b][c] = fmaxf(s + xa, 0.f);
        } else {
          float xr = x_l[b][0] * Wsr_l[0][c] + x_l[b][1] * Wsr_l[1][c];
          float v = fmaxf(s + xr, 0.f);
          r_tile[b][c] = v;
          if (t + 1 <= 32) r_hist_l[t + 1][b][c] = v;
        }
      }
      __syncthreads();
      if (tid < 128) {
        int b = tid >> 4, c = tid & 15;
        st64s(&st64[(tin * BB + b0 + b) * HH + c0 + c], pack2(a_tile[b][c], r_tile[b][c]));
      }
    }
    // ================= P: poll mu(t) =================
    if (tid < 128) {
      int igx = tid >> 3, p = tid & 7;
      const u64* mp = &mu64[(inst * 16 + igx) * 128 + jg * 8 + p];
      u64 v;
      for (;;) {
        v = ld64(mp);
        if ((unsigned)v != SENT_NAN && (unsigned)(v >> 32) != SENT_NAN) break;
      }
      muP[igx][2 * p]     = __uint_as_float((unsigned)v);
      muP[igx][2 * p + 1] = __uint_as_float((unsigned)(v >> 32));
    }
    if (t + 3 <= 63 && tid >= 128 && tid < 136) {  // mu slot re-sentinel
      st64s(&mu64[(rin * 16 + ig) * 128 + jg * 8 + (tid - 128)], SENT_NAN_PAIR);
    }
    __syncthreads();
    // ================= F: finish o(t) =================
    if (tid < 128) {
      int b = tid >> 4, c = tid & 15;
      float mv = 0.f;
      #pragma unroll
      for (int i = 0; i < 16; ++i) mv += muP[i][c];
      float v = fmaxf(g_l[c] * (ops[b][c] - mv * (1.0f / 128.0f)) + b_l[c], 0.f);
      o_tile[b][c] = v;
      if (t <= 32) o_hist[((t * 16 + jg) * BB + b0 + b) * 16 + c] = v;  // private, cached
    }
    __syncthreads();
    if (t >= 56 && tid < 80) {
      int b = tid / 10, n = tid % 10;
      float acc = 0.f;
      #pragma unroll
      for (int c = 0; c < 16; ++c) acc += o_tile[b][c] * Wy_l[c][n];
      atomicAdd(&out[(t - 56) * (BB * 10) + (b0 + b) * 10 + n], acc);
    }
    // ================= D(t+1): dot partials publish =================
    if (t < NSTEPS - 1) {
      int ns2 = ((t < 32) ? t : 32) + 1;    // slots s = 0..min(t,32)
      for (int sb = tid; sb < ns2 * 8; sb += 256) {
        int s = sb >> 3, b = sb & 7;
        float acc = 0.f;
        if (s == t) {
          #pragma unroll
          for (int c = 0; c < 16; ++c) acc += r_tile[b][c] * o_tile[b][c];
        } else {
          const float4* q = (const float4*)&o_hist[((s * 16 + jg) * BB + b0 + b) * 16];
          float4 q0 = q[0], q1 = q[1], q2 = q[2], q3 = q[3];
          acc = r_tile[b][0]  * q0.x + r_tile[b][1]  * q0.y + r_tile[b][2]  * q0.z + r_tile[b][3]  * q0.w
              + r_tile[b][4]  * q1.x + r_tile[b][5]  * q1.y + r_tile[b][6]  * q1.z + r_tile[b][7]  * q1.w
              + r_tile[b][8]  * q2.x + r_tile[b][9]  * q2.y + r_tile[b][10] * q2.z + r_tile[b][11] * q2.w
              + r_tile[b][12] * q3.x + r_tile[b][13] * q3.y + r_tile[b][14] * q3.z + r_tile[b][15] * q3.w;
        }
        st32f(&c_parts[((tin * 33 + s) * BB + b0 + b) * 16 + jg], acc);
      }
      if (t + 3 <= 63) {                    // c slot re-sentinel
        int ns3 = ((t + 2 < 32) ? t + 2 : 32) + 1;
        for (int sb = tid; sb < ns3 * 8; sb += 256) {
          int s = sb >> 3, b = sb & 7;
          st32f(&c_parts[((rin * 33 + s) * BB + b0 + b) * 16 + jg], -1.0f);
        }
      }
    }
  }
}

extern "C" void kernel_launch(void* const* d_in, const int* in_sizes, int n_in,
                              void* d_out, int out_size, void* d_ws, size_t ws_size,
                              hipStream_t stream) {
  if (ws_size < (size_t)WS_FLOATS * 4) return;   // ~7.1 MB scratch
  const float* x_in = (const float*)d_in[0];
  const float* W_sr = (const float*)d_in[1];
  const float* W_ma = (const float*)d_in[2];
  const float* W_ro = (const float*)d_in[3];
  const float* W_ao = (const float*)d_in[4];
  const float* W_ar = (const float*)d_in[5];
  const float* W_ra = (const float*)d_in[6];
  const float* W_a  = (const float*)d_in[7];
  const float* W_y  = (const float*)d_in[8];
  const float* g    = (const float*)d_in[9];
  const float* b    = (const float*)d_in[10];
  float* out = (float*)d_out;
  float* ws  = (float*)d_ws;

  hipLaunchKernelGGL(smn_init, dim3(256), dim3(256), 0, stream, ws, out);
  hipLaunchKernelGGL(smn_main, dim3(256), dim3(256), 0, stream,
                     x_in, W_sr, W_ma, W_ro, W_ao, W_ar, W_ra, W_a, W_y, g, b,
                     out, ws);
}